// Round 4
// baseline (266.054 us; speedup 1.0000x reference)
//
#include <hip/hip_runtime.h>
#include <math.h>

typedef unsigned short u16;
typedef unsigned int u32;
typedef __attribute__((ext_vector_type(4))) float f32x4;
typedef __attribute__((ext_vector_type(8))) short s16x8;

#define GLL16(g, l) __builtin_amdgcn_global_load_lds( \
    (const __attribute__((address_space(1))) void*)(g), \
    (__attribute__((address_space(3))) void*)(l), 16, 0, 0)

__device__ __forceinline__ u16 f2bf(float f) {
  union { float f; u32 u; } v; v.f = f;
  u32 r = v.u + 0x7FFFu + ((v.u >> 16) & 1u);
  return (u16)(r >> 16);
}
__device__ __forceinline__ float bf2f(u16 h) {
  union { u32 u; float f; } v; v.u = ((u32)h) << 16;
  return v.f;
}
// pack two floats to bf16x2 (round-half-up) in one v_perm
__device__ __forceinline__ u32 pk2bf(float lo, float hi) {
  union { float f; u32 u; } a, b; a.f = lo; b.f = hi;
  return __builtin_amdgcn_perm(b.u + 0x8000u, a.u + 0x8000u, 0x07060302u);
}
__device__ __forceinline__ float fexp2(float x) {
#if __has_builtin(__builtin_amdgcn_exp2f)
  return __builtin_amdgcn_exp2f(x);
#else
  return exp2f(x);
#endif
}

// ---------------- cast fp32 -> bf16 (packed) ----------------
__global__ __launch_bounds__(256) void cast_kernel(const float* __restrict__ src,
                                                   u16* __restrict__ dst, int n4) {
  int i = blockIdx.x * 256 + threadIdx.x;
  if (i >= n4) return;
  float4 v = ((const float4*)src)[i];
  uint2 o;
  o.x = (u32)f2bf(v.x) | ((u32)f2bf(v.y) << 16);
  o.y = (u32)f2bf(v.z) | ((u32)f2bf(v.w) << 16);
  ((uint2*)dst)[i] = o;
}

// ---------------- RMSNorm: one block per row of 1024 ----------------
__global__ __launch_bounds__(256) void rmsnorm_kernel(const float* __restrict__ x,
                                                      const float* __restrict__ wgt,
                                                      u16* __restrict__ h) {
  const int row = blockIdx.x, tid = threadIdx.x;
  const float4 v = *(const float4*)&x[(size_t)row * 1024 + tid * 4];
  float ss = v.x * v.x + v.y * v.y + v.z * v.z + v.w * v.w;
  ss += __shfl_xor(ss, 1);  ss += __shfl_xor(ss, 2);  ss += __shfl_xor(ss, 4);
  ss += __shfl_xor(ss, 8);  ss += __shfl_xor(ss, 16); ss += __shfl_xor(ss, 32);
  __shared__ float red[4];
  if ((tid & 63) == 0) red[tid >> 6] = ss;
  __syncthreads();
  const float tot = red[0] + red[1] + red[2] + red[3];
  const float s = rsqrtf(tot * (1.0f / 1024.0f) + 1e-6f);
  const float4 g = *(const float4*)&wgt[tid * 4];
  uint2 o;
  o.x = (u32)f2bf(v.x * s * g.x) | ((u32)f2bf(v.y * s * g.y) << 16);
  o.y = (u32)f2bf(v.z * s * g.z) | ((u32)f2bf(v.w * s * g.w) << 16);
  *(uint2*)&h[(size_t)row * 1024 + tid * 4] = o;
}

// ---------------- GEMM: C(MxN) = A(MxK) * Bt(NxK)^T, bf16 MFMA ----------------
template <int EPI>  // 0: write bf16 C. 1: write fp32 C = acc + resid
__global__ __launch_bounds__(256) void gemm_bt(const u16* __restrict__ A,
                                               const u16* __restrict__ Bt,
                                               u16* __restrict__ Cb,
                                               float* __restrict__ Cf,
                                               const float* __restrict__ resid,
                                               int M, int N, int K) {
  __shared__ __attribute__((aligned(16))) u16 As[128 * 32];
  __shared__ __attribute__((aligned(16))) u16 Bs[128 * 32];
  const int tid = threadIdx.x;
  const int w = tid >> 6, lane = tid & 63;
  const int quad = lane >> 4, l16 = lane & 15;
  const int gm0 = blockIdx.y * 128, gn0 = blockIdx.x * 128;
  const int wm = (w & 1) * 64, wn = (w >> 1) * 64;

  f32x4 acc[4][4] = {};

  for (int k0 = 0; k0 < K; k0 += 32) {
    __syncthreads();
    if (w < 2) {
      #pragma unroll
      for (int i = 0; i < 4; ++i) {
        int sb = (w * 4 + i) * 64;
        int slot = sb + lane;
        int m = slot >> 2, c = (slot & 3) ^ (m & 3);
        GLL16(A + (size_t)(gm0 + m) * K + k0 + c * 8, &As[sb * 8]);
      }
    } else {
      #pragma unroll
      for (int i = 0; i < 4; ++i) {
        int sb = ((w - 2) * 4 + i) * 64;
        int slot = sb + lane;
        int n = slot >> 2, c = (slot & 3) ^ (n & 3);
        GLL16(Bt + (size_t)(gn0 + n) * K + k0 + c * 8, &Bs[sb * 8]);
      }
    }
    __syncthreads();
    s16x8 aF[4], bF[4];
    #pragma unroll
    for (int i = 0; i < 4; ++i) {
      int m = wm + i * 16 + l16;
      aF[i] = *(const s16x8*)&As[(m * 4 + (quad ^ (m & 3))) * 8];
    }
    #pragma unroll
    for (int j = 0; j < 4; ++j) {
      int n = wn + j * 16 + l16;
      bF[j] = *(const s16x8*)&Bs[(n * 4 + (quad ^ (n & 3))) * 8];
    }
    #pragma unroll
    for (int i = 0; i < 4; ++i)
      #pragma unroll
      for (int j = 0; j < 4; ++j)
        acc[i][j] = __builtin_amdgcn_mfma_f32_16x16x32_bf16(aF[i], bF[j], acc[i][j], 0, 0, 0);
  }

  #pragma unroll
  for (int i = 0; i < 4; ++i) {
    int row0 = gm0 + wm + i * 16 + quad * 4;
    #pragma unroll
    for (int j = 0; j < 4; ++j) {
      int col = gn0 + wn + j * 16 + l16;
      #pragma unroll
      for (int r = 0; r < 4; ++r) {
        size_t idx = (size_t)(row0 + r) * N + col;
        if (EPI == 0) Cb[idx] = f2bf(acc[i][j][r]);
        else          Cf[idx] = acc[i][j][r] + resid[idx];
      }
    }
  }
}

// ---------------- RoPE + reorder ----------------
// qkv (4096 x 3072) bf16 -> Qr,Kr (bh,T,64), Vt (bh,64,T)
// Q pre-scaled by 0.125*log2(e) so attention uses exp2 directly.
__global__ __launch_bounds__(256) void rope_kernel(const u16* __restrict__ qkv,
                                                   u16* __restrict__ Qr,
                                                   u16* __restrict__ Kr,
                                                   u16* __restrict__ Vt) {
  const int tt = blockIdx.x, bh = blockIdx.y;
  const int b = bh >> 4, h = bh & 15;
  const int tid = threadIdx.x;
  const float QSCALE = 0.125f * 1.4426950408889634f;

  #pragma unroll
  for (int ii = 0; ii < 8; ++ii) {
    int idx = ii * 256 + tid;      // 64 tokens x 32 pairs
    int tl = idx >> 5, jj = idx & 31;
    int t = tt * 64 + tl;
    size_t mrow = (size_t)(b * 2048 + t) * 3072 + h * 64;
    float q1 = bf2f(qkv[mrow + jj]),        q2 = bf2f(qkv[mrow + 32 + jj]);
    float k1 = bf2f(qkv[mrow + 1024 + jj]), k2 = bf2f(qkv[mrow + 1024 + 32 + jj]);
    float invf = exp2f(-(float)jj * (13.287712379549449f / 32.0f));  // 10000^(-j/32)
    float ang = (float)t * invf;
    float sn, cs;
    sincosf(ang, &sn, &cs);
    size_t orow = (size_t)(bh * 2048 + t) * 64;
    Qr[orow + jj]      = f2bf((q1 * cs - q2 * sn) * QSCALE);
    Qr[orow + 32 + jj] = f2bf((q2 * cs + q1 * sn) * QSCALE);
    Kr[orow + jj]      = f2bf(k1 * cs - k2 * sn);
    Kr[orow + 32 + jj] = f2bf(k2 * cs + k1 * sn);
  }

  // V transpose 64x64 via LDS
  __shared__ __attribute__((aligned(16))) u16 Vl[64][72];
  for (int s = tid; s < 512; s += 256) {
    int r = s >> 3, c8 = (s & 7) * 8;
    *(uint4*)&Vl[r][c8] =
        *(const uint4*)&qkv[(size_t)(b * 2048 + tt * 64 + r) * 3072 + 2048 + h * 64 + c8];
  }
  __syncthreads();
  for (int s = tid; s < 512; s += 256) {
    int d = s >> 3, t8 = (s & 7) * 8;
    u16 tmp[8];
    #pragma unroll
    for (int k = 0; k < 8; ++k) tmp[k] = Vl[t8 + k][d];
    *(uint4*)&Vt[(size_t)(bh * 64 + d) * 2048 + tt * 64 + t8] = *(uint4*)tmp;
  }
}

// ---------------- Flash attention v4: 4-wave k-split ----------------
// Block = 256 threads = 4 waves, all sharing one (bh, 32-q tile).
// Wave w handles k-tiles j = w, w+4, ... (exact partial sums: no max shift,
// so combine = plain add of O and l across waves; staged via LDS at the end).
// No barriers inside the k-loop; each wave owns a private P transpose buffer.
__global__ __launch_bounds__(256, 4) void attn_kernel(const u16* __restrict__ Qr,
                                                      const u16* __restrict__ Kr,
                                                      const u16* __restrict__ Vt,
                                                      u16* __restrict__ AO) {
  __shared__ __attribute__((aligned(16))) u16 Pb[4][2][16 * 72];  // 18432 B
  __shared__ float Ls[4][2][64];                                  // 2048 B
  const int tid = threadIdx.x;
  const int w = tid >> 6, lane = tid & 63;
  const int quad = lane >> 4, l16 = lane & 15;
  const int id = blockIdx.x;
  const int bh = id & 31;                 // id%8 = bh%8 -> per-bh XCD affinity
  const int qi = 63 - (id >> 5);          // heavy q-tiles dispatched first
  const int q0 = qi * 32;
  const int jmax = qi >> 1;               // last (diagonal) k-tile index
  const int b = bh >> 4, h = bh & 15;
  const size_t qkb = (size_t)bh * (2048 * 64);
  const size_t vtb = (size_t)bh * (64 * 2048);
  u16* Pw = &Pb[w][0][0];

  // Q B-fragments direct from global: B[n=q(l16)][k=d(quad*8+j)]
  s16x8 bQ[2][2];
  #pragma unroll
  for (int s = 0; s < 2; ++s)
    #pragma unroll
    for (int hf = 0; hf < 2; ++hf)
      bQ[s][hf] = *(const s16x8*)&Qr[qkb + (size_t)(q0 + s * 16 + l16) * 64 + hf * 32 + quad * 8];

  f32x4 O[2][4] = {};
  float l_run[2] = {0.0f, 0.0f};

  auto body = [&](int j, bool masked) {
    // K fragments: A[m=key(l16)][k=d(quad*8+..)] = Kr[j*64+kt*16+l16][d slice]
    s16x8 aK[4][2], aV[4][2];
    #pragma unroll
    for (int kt = 0; kt < 4; ++kt) {
      const u16* kp = &Kr[qkb + (size_t)(j * 64 + kt * 16 + l16) * 64 + quad * 8];
      aK[kt][0] = *(const s16x8*)kp;
      aK[kt][1] = *(const s16x8*)(kp + 32);
    }
    // V fragments: A[m=d(l16)][k=key(quad*8+..)] = Vt[dt*16+l16][j*64 + key slice]
    #pragma unroll
    for (int dt = 0; dt < 4; ++dt) {
      const u16* vp = &Vt[vtb + (size_t)(dt * 16 + l16) * 2048 + j * 64 + quad * 8];
      aV[dt][0] = *(const s16x8*)vp;
      aV[dt][1] = *(const s16x8*)(vp + 32);
    }

    // S^T = K . Q^T  (C: row=key quad*4+r, col=q l16)
    f32x4 S[2][4];
    #pragma unroll
    for (int kt = 0; kt < 4; ++kt)
      #pragma unroll
      for (int s = 0; s < 2; ++s) {
        f32x4 z = {};
        z = __builtin_amdgcn_mfma_f32_16x16x32_bf16(aK[kt][0], bQ[s][0], z, 0, 0, 0);
        S[s][kt] = __builtin_amdgcn_mfma_f32_16x16x32_bf16(aK[kt][1], bQ[s][1], z, 0, 0, 0);
      }

    if (masked) {
      #pragma unroll
      for (int s = 0; s < 2; ++s) {
        int q = q0 + s * 16 + l16;
        #pragma unroll
        for (int kt = 0; kt < 4; ++kt) {
          int key0 = j * 64 + kt * 16 + quad * 4;
          #pragma unroll
          for (int r = 0; r < 4; ++r)
            if (key0 + r > q) S[s][kt][r] = -1e30f;
        }
      }
    }

    // exp2 + rowsum + pack P into this wave's LDS buffer
    #pragma unroll
    for (int s = 0; s < 2; ++s) {
      float sum = 0.0f;
      #pragma unroll
      for (int kt = 0; kt < 4; ++kt) {
        #pragma unroll
        for (int r = 0; r < 4; ++r) {
          float e = fexp2(S[s][kt][r]);
          S[s][kt][r] = e;
          sum += e;
        }
      }
      sum += __shfl_xor(sum, 16);
      sum += __shfl_xor(sum, 32);
      l_run[s] += sum;
      #pragma unroll
      for (int kt = 0; kt < 4; ++kt) {
        uint2 pw;
        pw.x = pk2bf(S[s][kt][0], S[s][kt][1]);
        pw.y = pk2bf(S[s][kt][2], S[s][kt][3]);
        *(uint2*)&Pw[s * 1152 + l16 * 72 + kt * 16 + quad * 4] = pw;
      }
    }

    // O^T += V^T . P^T   (B-frag of P from LDS; DS ops are wave-in-order)
    s16x8 bP[2][2];
    #pragma unroll
    for (int s = 0; s < 2; ++s) {
      bP[s][0] = *(const s16x8*)&Pw[s * 1152 + l16 * 72 + quad * 8];
      bP[s][1] = *(const s16x8*)&Pw[s * 1152 + l16 * 72 + 32 + quad * 8];
    }
    #pragma unroll
    for (int dt = 0; dt < 4; ++dt)
      #pragma unroll
      for (int s = 0; s < 2; ++s) {
        O[s][dt] = __builtin_amdgcn_mfma_f32_16x16x32_bf16(aV[dt][0], bP[s][0], O[s][dt], 0, 0, 0);
        O[s][dt] = __builtin_amdgcn_mfma_f32_16x16x32_bf16(aV[dt][1], bP[s][1], O[s][dt], 0, 0, 0);
      }
  };

  for (int j = w; j <= jmax; j += 4) body(j, j == jmax);

  // ---- cross-wave combine: O_tot = sum O_w, l_tot = sum l_w (exact) ----
  Ls[w][0][lane] = l_run[0];
  Ls[w][1][lane] = l_run[1];
  __syncthreads();  // k-loop done everywhere; Pb reusable as combine slots
  f32x4* slotA = (f32x4*)&Pb[0][0][0];  // 8 KB
  f32x4* slotB = (f32x4*)&Pb[2][0][0];  // 8 KB
  if (w == 1 || w == 3) {
    f32x4* slot = (w == 1) ? slotA : slotB;
    #pragma unroll
    for (int s = 0; s < 2; ++s)
      #pragma unroll
      for (int dt = 0; dt < 4; ++dt)
        slot[(s * 4 + dt) * 64 + lane] = O[s][dt];
  }
  __syncthreads();
  if (w == 0 || w == 2) {
    f32x4* slot = (w == 0) ? slotA : slotB;
    #pragma unroll
    for (int s = 0; s < 2; ++s)
      #pragma unroll
      for (int dt = 0; dt < 4; ++dt)
        O[s][dt] += slot[(s * 4 + dt) * 64 + lane];
  }
  __syncthreads();
  if (w == 2) {
    #pragma unroll
    for (int s = 0; s < 2; ++s)
      #pragma unroll
      for (int dt = 0; dt < 4; ++dt)
        slotA[(s * 4 + dt) * 64 + lane] = O[s][dt];
  }
  __syncthreads();
  if (w == 0) {
    #pragma unroll
    for (int s = 0; s < 2; ++s) {
      float l_tot = Ls[0][s][lane] + Ls[1][s][lane] + Ls[2][s][lane] + Ls[3][s][lane];
      float inv = __builtin_amdgcn_rcpf(l_tot);
      int q = q0 + s * 16 + l16;
      #pragma unroll
      for (int dt = 0; dt < 4; ++dt) {
        O[s][dt] += slotA[(s * 4 + dt) * 64 + lane];
        uint2 ow;
        ow.x = pk2bf(O[s][dt][0] * inv, O[s][dt][1] * inv);
        ow.y = pk2bf(O[s][dt][2] * inv, O[s][dt][3] * inv);
        *(uint2*)&AO[(size_t)(b * 2048 + q) * 1024 + h * 64 + dt * 16 + quad * 4] = ow;
      }
    }
  }
}

// ---------------- launcher ----------------
extern "C" void kernel_launch(void* const* d_in, const int* in_sizes, int n_in,
                              void* d_out, int out_size, void* d_ws, size_t ws_size,
                              hipStream_t stream) {
  const float* x      = (const float*)d_in[0];
  const float* norm_w = (const float*)d_in[1];
  const float* w_qkv  = (const float*)d_in[2];
  const float* w_out  = (const float*)d_in[3];
  float* out = (float*)d_out;

  u16* ws     = (u16*)d_ws;
  u16* wqkv_b = ws;                      // 3 145 728
  u16* wout_b = wqkv_b + 3145728;        // 1 048 576
  u16* h_b    = wout_b + 1048576;        // 4 194 304
  u16* qkv_b  = h_b + 4194304;           // 12 582 912
  u16* Qr     = qkv_b + 12582912;        // 4 194 304
  u16* Kr     = Qr + 4194304;            // 4 194 304
  u16* Vt     = Kr + 4194304;            // 4 194 304
  u16* AO     = Vt + 4194304;            // 4 194 304  (total ~75.5 MB)

  cast_kernel<<<3072, 256, 0, stream>>>(w_qkv, wqkv_b, 786432);
  cast_kernel<<<1024, 256, 0, stream>>>(w_out, wout_b, 262144);
  rmsnorm_kernel<<<4096, 256, 0, stream>>>(x, norm_w, h_b);
  gemm_bt<0><<<dim3(24, 32), 256, 0, stream>>>(h_b, wqkv_b, qkv_b, nullptr, nullptr,
                                               4096, 3072, 1024);
  rope_kernel<<<dim3(32, 32), 256, 0, stream>>>(qkv_b, Qr, Kr, Vt);
  attn_kernel<<<2048, 256, 0, stream>>>(Qr, Kr, Vt, AO);
  gemm_bt<1><<<dim3(8, 32), 256, 0, stream>>>(AO, wout_b, nullptr, out, x,
                                              4096, 1024, 1024);
}

// Round 5
// 221.662 us; speedup vs baseline: 1.2003x; 1.2003x over previous
//
#include <hip/hip_runtime.h>
#include <math.h>

typedef unsigned short u16;
typedef unsigned int u32;
typedef __attribute__((ext_vector_type(4))) float f32x4;
typedef __attribute__((ext_vector_type(8))) short s16x8;

#define GLL16(g, l) __builtin_amdgcn_global_load_lds( \
    (const __attribute__((address_space(1))) void*)(g), \
    (__attribute__((address_space(3))) void*)(l), 16, 0, 0)

__device__ __forceinline__ u16 f2bf(float f) {
  union { float f; u32 u; } v; v.f = f;
  u32 r = v.u + 0x7FFFu + ((v.u >> 16) & 1u);
  return (u16)(r >> 16);
}
__device__ __forceinline__ float bf2f(u16 h) {
  union { u32 u; float f; } v; v.u = ((u32)h) << 16;
  return v.f;
}
// pack two floats to bf16x2 (round-half-up) in one v_perm
__device__ __forceinline__ u32 pk2bf(float lo, float hi) {
  union { float f; u32 u; } a, b; a.f = lo; b.f = hi;
  return __builtin_amdgcn_perm(b.u + 0x8000u, a.u + 0x8000u, 0x07060302u);
}
__device__ __forceinline__ float fexp2(float x) {
#if __has_builtin(__builtin_amdgcn_exp2f)
  return __builtin_amdgcn_exp2f(x);
#else
  return exp2f(x);
#endif
}

// ---------------- cast fp32 -> bf16 (packed) ----------------
__global__ __launch_bounds__(256) void cast_kernel(const float* __restrict__ src,
                                                   u16* __restrict__ dst, int n4) {
  int i = blockIdx.x * 256 + threadIdx.x;
  if (i >= n4) return;
  float4 v = ((const float4*)src)[i];
  uint2 o;
  o.x = (u32)f2bf(v.x) | ((u32)f2bf(v.y) << 16);
  o.y = (u32)f2bf(v.z) | ((u32)f2bf(v.w) << 16);
  ((uint2*)dst)[i] = o;
}

// ---------------- RMSNorm: one block per row of 1024 ----------------
__global__ __launch_bounds__(256) void rmsnorm_kernel(const float* __restrict__ x,
                                                      const float* __restrict__ wgt,
                                                      u16* __restrict__ h) {
  const int row = blockIdx.x, tid = threadIdx.x;
  const float4 v = *(const float4*)&x[(size_t)row * 1024 + tid * 4];
  float ss = v.x * v.x + v.y * v.y + v.z * v.z + v.w * v.w;
  ss += __shfl_xor(ss, 1);  ss += __shfl_xor(ss, 2);  ss += __shfl_xor(ss, 4);
  ss += __shfl_xor(ss, 8);  ss += __shfl_xor(ss, 16); ss += __shfl_xor(ss, 32);
  __shared__ float red[4];
  if ((tid & 63) == 0) red[tid >> 6] = ss;
  __syncthreads();
  const float tot = red[0] + red[1] + red[2] + red[3];
  const float s = rsqrtf(tot * (1.0f / 1024.0f) + 1e-6f);
  const float4 g = *(const float4*)&wgt[tid * 4];
  uint2 o;
  o.x = (u32)f2bf(v.x * s * g.x) | ((u32)f2bf(v.y * s * g.y) << 16);
  o.y = (u32)f2bf(v.z * s * g.z) | ((u32)f2bf(v.w * s * g.w) << 16);
  *(uint2*)&h[(size_t)row * 1024 + tid * 4] = o;
}

// ---------------- GEMM: C(MxN) = A(MxK) * Bt(NxK)^T, bf16 MFMA ----------------
template <int EPI>  // 0: write bf16 C. 1: write fp32 C = acc + resid
__global__ __launch_bounds__(256) void gemm_bt(const u16* __restrict__ A,
                                               const u16* __restrict__ Bt,
                                               u16* __restrict__ Cb,
                                               float* __restrict__ Cf,
                                               const float* __restrict__ resid,
                                               int M, int N, int K) {
  __shared__ __attribute__((aligned(16))) u16 As[128 * 32];
  __shared__ __attribute__((aligned(16))) u16 Bs[128 * 32];
  const int tid = threadIdx.x;
  const int w = tid >> 6, lane = tid & 63;
  const int quad = lane >> 4, l16 = lane & 15;
  const int gm0 = blockIdx.y * 128, gn0 = blockIdx.x * 128;
  const int wm = (w & 1) * 64, wn = (w >> 1) * 64;

  f32x4 acc[4][4] = {};

  for (int k0 = 0; k0 < K; k0 += 32) {
    __syncthreads();
    if (w < 2) {
      #pragma unroll
      for (int i = 0; i < 4; ++i) {
        int sb = (w * 4 + i) * 64;
        int slot = sb + lane;
        int m = slot >> 2, c = (slot & 3) ^ (m & 3);
        GLL16(A + (size_t)(gm0 + m) * K + k0 + c * 8, &As[sb * 8]);
      }
    } else {
      #pragma unroll
      for (int i = 0; i < 4; ++i) {
        int sb = ((w - 2) * 4 + i) * 64;
        int slot = sb + lane;
        int n = slot >> 2, c = (slot & 3) ^ (n & 3);
        GLL16(Bt + (size_t)(gn0 + n) * K + k0 + c * 8, &Bs[sb * 8]);
      }
    }
    __syncthreads();
    s16x8 aF[4], bF[4];
    #pragma unroll
    for (int i = 0; i < 4; ++i) {
      int m = wm + i * 16 + l16;
      aF[i] = *(const s16x8*)&As[(m * 4 + (quad ^ (m & 3))) * 8];
    }
    #pragma unroll
    for (int j = 0; j < 4; ++j) {
      int n = wn + j * 16 + l16;
      bF[j] = *(const s16x8*)&Bs[(n * 4 + (quad ^ (n & 3))) * 8];
    }
    #pragma unroll
    for (int i = 0; i < 4; ++i)
      #pragma unroll
      for (int j = 0; j < 4; ++j)
        acc[i][j] = __builtin_amdgcn_mfma_f32_16x16x32_bf16(aF[i], bF[j], acc[i][j], 0, 0, 0);
  }

  #pragma unroll
  for (int i = 0; i < 4; ++i) {
    int row0 = gm0 + wm + i * 16 + quad * 4;
    #pragma unroll
    for (int j = 0; j < 4; ++j) {
      int col = gn0 + wn + j * 16 + l16;
      #pragma unroll
      for (int r = 0; r < 4; ++r) {
        size_t idx = (size_t)(row0 + r) * N + col;
        if (EPI == 0) Cb[idx] = f2bf(acc[i][j][r]);
        else          Cf[idx] = acc[i][j][r] + resid[idx];
      }
    }
  }
}

// ---------------- RoPE + reorder ----------------
// qkv (4096 x 3072) bf16 -> Qr,Kr (bh,T,64), Vt (bh,64,T)
// Q pre-scaled by 0.125*log2(e) so attention uses exp2 directly.
__global__ __launch_bounds__(256) void rope_kernel(const u16* __restrict__ qkv,
                                                   u16* __restrict__ Qr,
                                                   u16* __restrict__ Kr,
                                                   u16* __restrict__ Vt) {
  const int tt = blockIdx.x, bh = blockIdx.y;
  const int b = bh >> 4, h = bh & 15;
  const int tid = threadIdx.x;
  const float QSCALE = 0.125f * 1.4426950408889634f;

  #pragma unroll
  for (int ii = 0; ii < 8; ++ii) {
    int idx = ii * 256 + tid;      // 64 tokens x 32 pairs
    int tl = idx >> 5, jj = idx & 31;
    int t = tt * 64 + tl;
    size_t mrow = (size_t)(b * 2048 + t) * 3072 + h * 64;
    float q1 = bf2f(qkv[mrow + jj]),        q2 = bf2f(qkv[mrow + 32 + jj]);
    float k1 = bf2f(qkv[mrow + 1024 + jj]), k2 = bf2f(qkv[mrow + 1024 + 32 + jj]);
    float invf = exp2f(-(float)jj * (13.287712379549449f / 32.0f));  // 10000^(-j/32)
    float ang = (float)t * invf;
    float sn, cs;
    sincosf(ang, &sn, &cs);
    size_t orow = (size_t)(bh * 2048 + t) * 64;
    Qr[orow + jj]      = f2bf((q1 * cs - q2 * sn) * QSCALE);
    Qr[orow + 32 + jj] = f2bf((q2 * cs + q1 * sn) * QSCALE);
    Kr[orow + jj]      = f2bf(k1 * cs - k2 * sn);
    Kr[orow + 32 + jj] = f2bf(k2 * cs + k1 * sn);
  }

  // V transpose 64x64 via LDS
  __shared__ __attribute__((aligned(16))) u16 Vl[64][72];
  for (int s = tid; s < 512; s += 256) {
    int r = s >> 3, c8 = (s & 7) * 8;
    *(uint4*)&Vl[r][c8] =
        *(const uint4*)&qkv[(size_t)(b * 2048 + tt * 64 + r) * 3072 + 2048 + h * 64 + c8];
  }
  __syncthreads();
  for (int s = tid; s < 512; s += 256) {
    int d = s >> 3, t8 = (s & 7) * 8;
    u16 tmp[8];
    #pragma unroll
    for (int k = 0; k < 8; ++k) tmp[k] = Vl[t8 + k][d];
    *(uint4*)&Vt[(size_t)(bh * 64 + d) * 2048 + tt * 64 + t8] = *(uint4*)tmp;
  }
}

// ---------------- Flash attention v5: 2-wave k-split, no VGPR cap ----------------
// Block = 128 threads = 2 waves sharing one (bh, 32-q tile).
// Wave w handles k-tiles j = w, w+2, ... Exact partial sums (no max shift),
// so the cross-wave combine is a plain add of O and l, staged once via LDS.
// No barriers in the k-loop; per-wave private P transpose buffers.
// NOTE: no min-waves clause — R4's __launch_bounds__(256,4) capped VGPRs at 64
// and spilled 192 MB to scratch. Working set is ~100 VGPR + 32 AGPR.
__global__ __launch_bounds__(128) void attn_kernel(const u16* __restrict__ Qr,
                                                   const u16* __restrict__ Kr,
                                                   const u16* __restrict__ Vt,
                                                   u16* __restrict__ AO) {
  __shared__ __attribute__((aligned(16))) u16 Pb[2][2][16 * 72];  // 9216 B
  __shared__ float Ls[2][64];                                     // 512 B
  const int tid = threadIdx.x;
  const int w = tid >> 6, lane = tid & 63;
  const int quad = lane >> 4, l16 = lane & 15;
  const int id = blockIdx.x;
  const int bh = id & 31;                 // id%8 = bh%8 -> per-bh XCD affinity
  const int qi = 63 - (id >> 5);          // heavy q-tiles dispatched first
  const int q0 = qi * 32;
  const int jmax = qi >> 1;               // last (diagonal) k-tile index
  const int b = bh >> 4, h = bh & 15;
  const size_t qkb = (size_t)bh * (2048 * 64);
  const size_t vtb = (size_t)bh * (64 * 2048);
  u16* Pw = &Pb[w][0][0];

  // Q B-fragments direct from global: B[n=q(l16)][k=d(quad*8+j)]
  s16x8 bQ[2][2];
  #pragma unroll
  for (int s = 0; s < 2; ++s)
    #pragma unroll
    for (int hf = 0; hf < 2; ++hf)
      bQ[s][hf] = *(const s16x8*)&Qr[qkb + (size_t)(q0 + s * 16 + l16) * 64 + hf * 32 + quad * 8];

  f32x4 O[2][4] = {};
  float l_run[2] = {0.0f, 0.0f};

  auto body = [&](int j, bool masked) {
    // K fragments: A[m=key(l16)][k=d(quad*8+..)] = Kr[j*64+kt*16+l16][d slice]
    s16x8 aK[4][2], aV[4][2];
    #pragma unroll
    for (int kt = 0; kt < 4; ++kt) {
      const u16* kp = &Kr[qkb + (size_t)(j * 64 + kt * 16 + l16) * 64 + quad * 8];
      aK[kt][0] = *(const s16x8*)kp;
      aK[kt][1] = *(const s16x8*)(kp + 32);
    }
    // V fragments: A[m=d(l16)][k=key(quad*8+..)] = Vt[dt*16+l16][j*64 + key slice]
    #pragma unroll
    for (int dt = 0; dt < 4; ++dt) {
      const u16* vp = &Vt[vtb + (size_t)(dt * 16 + l16) * 2048 + j * 64 + quad * 8];
      aV[dt][0] = *(const s16x8*)vp;
      aV[dt][1] = *(const s16x8*)(vp + 32);
    }

    // S^T = K . Q^T  (C: row=key quad*4+r, col=q l16)
    f32x4 S[2][4];
    #pragma unroll
    for (int kt = 0; kt < 4; ++kt)
      #pragma unroll
      for (int s = 0; s < 2; ++s) {
        f32x4 z = {};
        z = __builtin_amdgcn_mfma_f32_16x16x32_bf16(aK[kt][0], bQ[s][0], z, 0, 0, 0);
        S[s][kt] = __builtin_amdgcn_mfma_f32_16x16x32_bf16(aK[kt][1], bQ[s][1], z, 0, 0, 0);
      }

    if (masked) {
      #pragma unroll
      for (int s = 0; s < 2; ++s) {
        int q = q0 + s * 16 + l16;
        #pragma unroll
        for (int kt = 0; kt < 4; ++kt) {
          int key0 = j * 64 + kt * 16 + quad * 4;
          #pragma unroll
          for (int r = 0; r < 4; ++r)
            if (key0 + r > q) S[s][kt][r] = -1e30f;
        }
      }
    }

    // exp2 + rowsum + pack P into this wave's LDS buffer
    #pragma unroll
    for (int s = 0; s < 2; ++s) {
      float sum = 0.0f;
      #pragma unroll
      for (int kt = 0; kt < 4; ++kt) {
        #pragma unroll
        for (int r = 0; r < 4; ++r) {
          float e = fexp2(S[s][kt][r]);
          S[s][kt][r] = e;
          sum += e;
        }
      }
      sum += __shfl_xor(sum, 16);
      sum += __shfl_xor(sum, 32);
      l_run[s] += sum;
      #pragma unroll
      for (int kt = 0; kt < 4; ++kt) {
        uint2 pw;
        pw.x = pk2bf(S[s][kt][0], S[s][kt][1]);
        pw.y = pk2bf(S[s][kt][2], S[s][kt][3]);
        *(uint2*)&Pw[s * 1152 + l16 * 72 + kt * 16 + quad * 4] = pw;
      }
    }

    // O^T += V^T . P^T   (B-frag of P from LDS; DS ops are wave-in-order)
    s16x8 bP[2][2];
    #pragma unroll
    for (int s = 0; s < 2; ++s) {
      bP[s][0] = *(const s16x8*)&Pw[s * 1152 + l16 * 72 + quad * 8];
      bP[s][1] = *(const s16x8*)&Pw[s * 1152 + l16 * 72 + 32 + quad * 8];
    }
    #pragma unroll
    for (int dt = 0; dt < 4; ++dt)
      #pragma unroll
      for (int s = 0; s < 2; ++s) {
        O[s][dt] = __builtin_amdgcn_mfma_f32_16x16x32_bf16(aV[dt][0], bP[s][0], O[s][dt], 0, 0, 0);
        O[s][dt] = __builtin_amdgcn_mfma_f32_16x16x32_bf16(aV[dt][1], bP[s][1], O[s][dt], 0, 0, 0);
      }
  };

  for (int j = w; j <= jmax; j += 2) body(j, j == jmax);

  // ---- cross-wave combine: O_tot = O_0 + O_1, l_tot = l_0 + l_1 (exact) ----
  __syncthreads();  // both waves done with their k-loops (Pb now reusable)
  f32x4* slot = (f32x4*)&Pb[0][0][0];  // 8192 B, fits in 9216 B Pb
  if (w == 1) {
    Ls[0][lane] = l_run[0];
    Ls[1][lane] = l_run[1];
    #pragma unroll
    for (int s = 0; s < 2; ++s)
      #pragma unroll
      for (int dt = 0; dt < 4; ++dt)
        slot[(s * 4 + dt) * 64 + lane] = O[s][dt];
  }
  __syncthreads();
  if (w == 0) {
    #pragma unroll
    for (int s = 0; s < 2; ++s) {
      float l_tot = l_run[s] + Ls[s][lane];
      float inv = __builtin_amdgcn_rcpf(l_tot);
      int q = q0 + s * 16 + l16;
      #pragma unroll
      for (int dt = 0; dt < 4; ++dt) {
        O[s][dt] += slot[(s * 4 + dt) * 64 + lane];
        uint2 ow;
        ow.x = pk2bf(O[s][dt][0] * inv, O[s][dt][1] * inv);
        ow.y = pk2bf(O[s][dt][2] * inv, O[s][dt][3] * inv);
        *(uint2*)&AO[(size_t)(b * 2048 + q) * 1024 + h * 64 + dt * 16 + quad * 4] = ow;
      }
    }
  }
}

// ---------------- launcher ----------------
extern "C" void kernel_launch(void* const* d_in, const int* in_sizes, int n_in,
                              void* d_out, int out_size, void* d_ws, size_t ws_size,
                              hipStream_t stream) {
  const float* x      = (const float*)d_in[0];
  const float* norm_w = (const float*)d_in[1];
  const float* w_qkv  = (const float*)d_in[2];
  const float* w_out  = (const float*)d_in[3];
  float* out = (float*)d_out;

  u16* ws     = (u16*)d_ws;
  u16* wqkv_b = ws;                      // 3 145 728
  u16* wout_b = wqkv_b + 3145728;        // 1 048 576
  u16* h_b    = wout_b + 1048576;        // 4 194 304
  u16* qkv_b  = h_b + 4194304;           // 12 582 912
  u16* Qr     = qkv_b + 12582912;        // 4 194 304
  u16* Kr     = Qr + 4194304;            // 4 194 304
  u16* Vt     = Kr + 4194304;            // 4 194 304
  u16* AO     = Vt + 4194304;            // 4 194 304  (total ~75.5 MB)

  cast_kernel<<<3072, 256, 0, stream>>>(w_qkv, wqkv_b, 786432);
  cast_kernel<<<1024, 256, 0, stream>>>(w_out, wout_b, 262144);
  rmsnorm_kernel<<<4096, 256, 0, stream>>>(x, norm_w, h_b);
  gemm_bt<0><<<dim3(24, 32), 256, 0, stream>>>(h_b, wqkv_b, qkv_b, nullptr, nullptr,
                                               4096, 3072, 1024);
  rope_kernel<<<dim3(32, 32), 256, 0, stream>>>(qkv_b, Qr, Kr, Vt);
  attn_kernel<<<2048, 128, 0, stream>>>(Qr, Kr, Vt, AO);
  gemm_bt<1><<<dim3(8, 32), 256, 0, stream>>>(AO, wout_b, nullptr, out, x,
                                              4096, 1024, 1024);
}